// Round 1
// baseline (626.682 us; speedup 1.0000x reference)
//
#include <hip/hip_runtime.h>
#include <cstdint>
#include <cstddef>

#define BB 4
#define SS 2048
#define DD 1024
#define HH 16

typedef __bf16 bf16;
typedef __bf16 bf16x8 __attribute__((ext_vector_type(8)));
typedef __bf16 bf16x4 __attribute__((ext_vector_type(4)));
typedef float f32x4 __attribute__((ext_vector_type(4)));

typedef __attribute__((address_space(1))) const void* as1_cvoid;
typedef __attribute__((address_space(3))) void* as3_void;

__device__ __forceinline__ void gload_lds16(const void* g, void* l) {
  __builtin_amdgcn_global_load_lds((as1_cvoid)g, (as3_void)l, 16, 0, 0);
}

// ---------------- K0: per-batch masked count ----------------
__global__ void mask_count_kernel(const unsigned char* __restrict__ mask, int* __restrict__ nm) {
  int wid = threadIdx.x >> 6, lane = threadIdx.x & 63;
  if (wid >= BB) return;
  int s = 0;
  for (int i = lane; i < SS; i += 64) s += (mask[wid * SS + i] != 0) ? 1 : 0;
#pragma unroll
  for (int m = 1; m < 64; m <<= 1) s += __shfl_xor(s, m);
  if (lane == 0) nm[wid] = s;
}

// ---------------- K1: f32 -> bf16 convert ----------------
__global__ void cvt_kernel(const float* __restrict__ src, bf16* __restrict__ dst, int n4) {
  int stride = gridDim.x * blockDim.x;
  for (int i = blockIdx.x * blockDim.x + threadIdx.x; i < n4; i += stride) {
    float4 v = ((const float4*)src)[i];
    bf16x4 o;
    o[0] = (bf16)v.x; o[1] = (bf16)v.y; o[2] = (bf16)v.z; o[3] = (bf16)v.w;
    ((bf16x4*)dst)[i] = o;
  }
}

// ---------------- K2/K5: C[M,N] = A[M,K] @ B[N,K]^T (bf16 in, bf16/f32 out) ----------------
template <bool F32OUT>
__global__ void __launch_bounds__(256) gemm_bt_kernel(const bf16* __restrict__ A,
                                                      const bf16* __restrict__ Bm,
                                                      void* __restrict__ Cout,
                                                      int M, int N, int K) {
  __shared__ bf16 Ab[128 * 32];
  __shared__ bf16 Bb[128 * 32];
  const int tid = threadIdx.x;
  const int wid = tid >> 6, lane = tid & 63;
  const int lr = lane & 15, lg = lane >> 4;
  const int m0 = blockIdx.y * 128, n0 = blockIdx.x * 128;
  const int wm = (wid >> 1) * 64, wn = (wid & 1) * 64;
  f32x4 acc[4][4] = {};
  for (int k0 = 0; k0 < K; k0 += 32) {
    __syncthreads();  // protect LDS from previous iteration's readers
#pragma unroll
    for (int i = 0; i < 2; ++i) {
      int o = (wid * 2 + i) * 1024 + lane * 16;  // byte offset into 8KB tile
      int row = o >> 6;                          // 64B per row (32 bf16)
      int ke = (o & 63) >> 1;                    // element offset in K
      gload_lds16(A + (size_t)(m0 + row) * K + k0 + ke, (char*)Ab + o);
      gload_lds16(Bm + (size_t)(n0 + row) * K + k0 + ke, (char*)Bb + o);
    }
    __syncthreads();  // staging visible (compiler drains vmcnt before barrier)
    bf16x8 af[4], bf_[4];
#pragma unroll
    for (int i = 0; i < 4; ++i) af[i] = *(const bf16x8*)&Ab[(wm + i * 16 + lr) * 32 + lg * 8];
#pragma unroll
    for (int j = 0; j < 4; ++j) bf_[j] = *(const bf16x8*)&Bb[(wn + j * 16 + lr) * 32 + lg * 8];
#pragma unroll
    for (int i = 0; i < 4; ++i)
#pragma unroll
      for (int j = 0; j < 4; ++j)
        acc[i][j] = __builtin_amdgcn_mfma_f32_16x16x32_bf16(af[i], bf_[j], acc[i][j], 0, 0, 0);
  }
#pragma unroll
  for (int i = 0; i < 4; ++i)
#pragma unroll
    for (int j = 0; j < 4; ++j)
#pragma unroll
      for (int r = 0; r < 4; ++r) {
        int row = m0 + wm + i * 16 + lg * 4 + r;
        int col = n0 + wn + j * 16 + lr;
        if (F32OUT)
          ((float*)Cout)[(size_t)row * N + col] = acc[i][j][r];
        else
          ((bf16*)Cout)[(size_t)row * N + col] = (bf16)acc[i][j][r];
      }
}

// ---------------- K3: RoPE + RMSNorm + per-dim scale + V transpose ----------------
__global__ void __launch_bounds__(256) rope_rms_kernel(
    const bf16* __restrict__ Qraw, const bf16* __restrict__ Kraw, const bf16* __restrict__ Vraw,
    const float* __restrict__ qls, const float* __restrict__ kls, const float* __restrict__ pds,
    const int* __restrict__ nm,
    bf16* __restrict__ Qp, bf16* __restrict__ Kp, bf16* __restrict__ Vt) {
  __shared__ bf16 Vlds[64][72];
  const int s0 = blockIdx.x * 64;
  const int bh = blockIdx.y;  // b*H + h
  const int b = bh >> 4, h = bh & 15;
  const int wid = threadIdx.x >> 6, l = threadIdx.x & 63;
  const int nmb = nm[b];
  // LOG2_E / sqrt(64) * softplus(per_dim_scale[l]) folded with q_ln_scale
  const float qsc = qls[l] * 0.1803368801111601f * log1pf(__expf(pds[l]));
  const float ksc = kls[l];
  const float inv_ts = __expf((float)(l & 31) * (-9.210340371976184f / 32.0f));  // 10000^{-j/32}
  for (int i = 0; i < 16; ++i) {
    int s = s0 + wid * 16 + i;
    size_t off = ((size_t)(b * SS + s)) * DD + h * 64 + l;
    float q = (float)Qraw[off], k = (float)Kraw[off], v = (float)Vraw[off];
    float ang = (float)(s - nmb) * inv_ts;
    float sn, cs;
    sincosf(ang, &sn, &cs);
    float qo = __shfl_xor(q, 32), ko = __shfl_xor(k, 32);
    float qr = (l < 32) ? (q * cs - qo * sn) : (q * cs + qo * sn);
    float kr = (l < 32) ? (k * cs - ko * sn) : (k * cs + ko * sn);
    float sq = qr * qr, sk = kr * kr;
#pragma unroll
    for (int m = 1; m < 64; m <<= 1) {
      sq += __shfl_xor(sq, m);
      sk += __shfl_xor(sk, m);
    }
    float qout = qr * rsqrtf(sq * (1.0f / 64.0f) + 1e-6f) * qsc;
    float kout = kr * rsqrtf(sk * (1.0f / 64.0f) + 1e-6f) * ksc;
    size_t po = ((size_t)bh * SS + s) * 64 + l;
    Qp[po] = (bf16)qout;
    Kp[po] = (bf16)kout;
    Vlds[wid * 16 + i][l] = (bf16)v;
  }
  __syncthreads();
  // coalesced transposed V write: Vt[b,h,d,s]
  int d = threadIdx.x >> 2, sc = (threadIdx.x & 3) * 16;
  bf16x8 v0, v1;
#pragma unroll
  for (int ii = 0; ii < 8; ++ii) v0[ii] = Vlds[sc + ii][d];
#pragma unroll
  for (int ii = 0; ii < 8; ++ii) v1[ii] = Vlds[sc + 8 + ii][d];
  size_t vo = ((size_t)bh * 64 + d) * SS + s0 + sc;
  *(bf16x8*)(Vt + vo) = v0;
  *(bf16x8*)(Vt + vo + 8) = v1;
}

// ---------------- K4: causal flash attention ----------------
__global__ void __launch_bounds__(256) flash_kernel(
    const bf16* __restrict__ Qp, const bf16* __restrict__ Kp, const bf16* __restrict__ Vt,
    bf16* __restrict__ O, const int* __restrict__ nm) {
  __shared__ bf16 Plds[4][16][72];
  const int q0 = blockIdx.x * 64;
  const int bh = blockIdx.y;
  const int b = bh >> 4, h = bh & 15;
  const int wid = threadIdx.x >> 6, lane = threadIdx.x & 63;
  const int lr = lane & 15, lg = lane >> 4;
  const int nmb = nm[b];
  const bf16* Qbase = Qp + ((size_t)bh * SS + q0 + wid * 16) * 64;
  bf16x8 qf0 = *(const bf16x8*)(Qbase + (size_t)lr * 64 + lg * 8);
  bf16x8 qf1 = *(const bf16x8*)(Qbase + (size_t)lr * 64 + 32 + lg * 8);
  float m_r[4], l_r[4];
  f32x4 o_acc[4] = {};
#pragma unroll
  for (int r = 0; r < 4; ++r) {
    m_r[r] = -1e30f;
    l_r[r] = 0.f;
  }
  const int qrow0 = q0 + wid * 16 + lg * 4;
  const int ntiles = blockIdx.x + 1;  // causal: kv tiles 0..q-tile inclusive
  for (int t = 0; t < ntiles; ++t) {
    const int kv0 = t * 64;
    f32x4 s[4];
#pragma unroll
    for (int j = 0; j < 4; ++j) {
      const bf16* kb = Kp + ((size_t)bh * SS + kv0 + j * 16 + lr) * 64 + lg * 8;
      bf16x8 kf0 = *(const bf16x8*)kb;
      bf16x8 kf1 = *(const bf16x8*)(kb + 32);
      f32x4 z = {};
      z = __builtin_amdgcn_mfma_f32_16x16x32_bf16(qf0, kf0, z, 0, 0, 0);
      z = __builtin_amdgcn_mfma_f32_16x16x32_bf16(qf1, kf1, z, 0, 0, 0);
      s[j] = z;
    }
    // causal + prefix mask
#pragma unroll
    for (int j = 0; j < 4; ++j) {
      int col = kv0 + j * 16 + lr;
#pragma unroll
      for (int r = 0; r < 4; ++r)
        if (col > qrow0 + r || col < nmb) s[j][r] = -1e30f;
    }
    // per-row max across 64 kv (16 lanes x 4 col-tiles)
    float pm[4];
#pragma unroll
    for (int r = 0; r < 4; ++r)
      pm[r] = fmaxf(fmaxf(s[0][r], s[1][r]), fmaxf(s[2][r], s[3][r]));
#pragma unroll
    for (int m = 1; m < 16; m <<= 1)
#pragma unroll
      for (int r = 0; r < 4; ++r) pm[r] = fmaxf(pm[r], __shfl_xor(pm[r], m));
    float scl[4], rs[4], p[4][4];
#pragma unroll
    for (int r = 0; r < 4; ++r) {
      float mn = fmaxf(m_r[r], pm[r]);
      scl[r] = __expf(m_r[r] - mn);
      m_r[r] = mn;
      rs[r] = 0.f;
    }
#pragma unroll
    for (int j = 0; j < 4; ++j)
#pragma unroll
      for (int r = 0; r < 4; ++r) {
        p[j][r] = __expf(s[j][r] - m_r[r]);
        rs[r] += p[j][r];
      }
#pragma unroll
    for (int m = 1; m < 16; m <<= 1)
#pragma unroll
      for (int r = 0; r < 4; ++r) rs[r] += __shfl_xor(rs[r], m);
    f32x4 scv;
#pragma unroll
    for (int r = 0; r < 4; ++r) {
      l_r[r] = l_r[r] * scl[r] + rs[r];
      scv[r] = scl[r];
    }
#pragma unroll
    for (int j = 0; j < 4; ++j) o_acc[j] *= scv;
    // P (C-layout) -> LDS -> A-fragment layout. Per-wave region, no barrier needed.
#pragma unroll
    for (int j = 0; j < 4; ++j)
#pragma unroll
      for (int r = 0; r < 4; ++r) Plds[wid][lg * 4 + r][j * 16 + lr] = (bf16)p[j][r];
    bf16x8 pa0 = *(const bf16x8*)&Plds[wid][lr][lg * 8];
    bf16x8 pa1 = *(const bf16x8*)&Plds[wid][lr][32 + lg * 8];
#pragma unroll
    for (int j = 0; j < 4; ++j) {
      const bf16* vb = Vt + ((size_t)bh * 64 + j * 16 + lr) * SS + kv0 + lg * 8;
      bf16x8 vf0 = *(const bf16x8*)vb;
      bf16x8 vf1 = *(const bf16x8*)(vb + 32);
      o_acc[j] = __builtin_amdgcn_mfma_f32_16x16x32_bf16(pa0, vf0, o_acc[j], 0, 0, 0);
      o_acc[j] = __builtin_amdgcn_mfma_f32_16x16x32_bf16(pa1, vf1, o_acc[j], 0, 0, 0);
    }
  }
  f32x4 inv;
#pragma unroll
  for (int r = 0; r < 4; ++r) inv[r] = 1.0f / l_r[r];
#pragma unroll
  for (int j = 0; j < 4; ++j) {
    f32x4 ov = o_acc[j] * inv;
#pragma unroll
    for (int r = 0; r < 4; ++r) {
      int srow = q0 + wid * 16 + lg * 4 + r;
      O[((size_t)(b * SS + srow)) * DD + h * 64 + j * 16 + lr] = (bf16)ov[r];
    }
  }
}

// ---------------- host launch ----------------
extern "C" void kernel_launch(void* const* d_in, const int* in_sizes, int n_in,
                              void* d_out, int out_size, void* d_ws, size_t ws_size,
                              hipStream_t stream) {
  const float* X = (const float*)d_in[0];
  const float* Wq = (const float*)d_in[1];
  const float* Wk = (const float*)d_in[2];
  const float* Wv = (const float*)d_in[3];
  const float* Wo = (const float*)d_in[4];
  const float* qls = (const float*)d_in[5];
  const float* kls = (const float*)d_in[6];
  const float* pds = (const float*)d_in[7];
  const unsigned char* mask = (const unsigned char*)d_in[8];

  char* ws = (char*)d_ws;
  size_t off = 0;
  auto alloc = [&](size_t bytes) {
    char* p = ws + off;
    off += (bytes + 255) & ~(size_t)255;
    return p;
  };
  const size_t NTOK = (size_t)BB * SS;  // 8192
  int* nm = (int*)alloc(16);
  bf16* Xb = (bf16*)alloc(NTOK * DD * 2);
  bf16* Wqb = (bf16*)alloc((size_t)DD * DD * 2);
  bf16* Wkb = (bf16*)alloc((size_t)DD * DD * 2);
  bf16* Wvb = (bf16*)alloc((size_t)DD * DD * 2);
  bf16* Wob = (bf16*)alloc((size_t)DD * DD * 2);
  bf16* Qraw = (bf16*)alloc(NTOK * DD * 2);
  bf16* Kraw = (bf16*)alloc(NTOK * DD * 2);
  bf16* Vraw = (bf16*)alloc(NTOK * DD * 2);
  bf16* Kp = (bf16*)alloc(NTOK * DD * 2);
  bf16* Vt = (bf16*)alloc(NTOK * DD * 2);
  bf16* Qp = Xb;    // alias: Xb dead after QKV GEMMs
  bf16* Oat = Qraw; // alias: Qraw dead after rope kernel

  mask_count_kernel<<<1, 256, 0, stream>>>(mask, nm);
  cvt_kernel<<<1024, 256, 0, stream>>>(X, Xb, (int)(NTOK * DD / 4));
  cvt_kernel<<<256, 256, 0, stream>>>(Wq, Wqb, DD * DD / 4);
  cvt_kernel<<<256, 256, 0, stream>>>(Wk, Wkb, DD * DD / 4);
  cvt_kernel<<<256, 256, 0, stream>>>(Wv, Wvb, DD * DD / 4);
  cvt_kernel<<<256, 256, 0, stream>>>(Wo, Wob, DD * DD / 4);

  dim3 gg(DD / 128, NTOK / 128);  // (8, 64)
  gemm_bt_kernel<false><<<gg, 256, 0, stream>>>(Xb, Wqb, Qraw, (int)NTOK, DD, DD);
  gemm_bt_kernel<false><<<gg, 256, 0, stream>>>(Xb, Wkb, Kraw, (int)NTOK, DD, DD);
  gemm_bt_kernel<false><<<gg, 256, 0, stream>>>(Xb, Wvb, Vraw, (int)NTOK, DD, DD);

  rope_rms_kernel<<<dim3(SS / 64, BB * HH), 256, 0, stream>>>(Qraw, Kraw, Vraw, qls, kls, pds,
                                                              nm, Qp, Kp, Vt);
  flash_kernel<<<dim3(SS / 64, BB * HH), 256, 0, stream>>>(Qp, Kp, Vt, Oat, nm);
  gemm_bt_kernel<true><<<gg, 256, 0, stream>>>(Oat, Wob, d_out, (int)NTOK, DD, DD);
}

// Round 2
// 338.056 us; speedup vs baseline: 1.8538x; 1.8538x over previous
//
#include <hip/hip_runtime.h>
#include <cstdint>
#include <cstddef>

#define BB 4
#define SS 2048
#define DD 1024
#define HH 16

typedef __bf16 bf16;
typedef __bf16 bf16x8 __attribute__((ext_vector_type(8)));
typedef __bf16 bf16x4 __attribute__((ext_vector_type(4)));
typedef float f32x4 __attribute__((ext_vector_type(4)));
typedef unsigned int u32;

typedef __attribute__((address_space(1))) const void* as1_cvoid;
typedef __attribute__((address_space(3))) void* as3_void;

__device__ __forceinline__ void gload_lds16(const void* g, void* l) {
  __builtin_amdgcn_global_load_lds((as1_cvoid)g, (as3_void)l, 16, 0, 0);
}

__device__ __forceinline__ u32 pack2(float lo, float hi) {
  union { bf16 h[2]; u32 u; } z;
  z.h[0] = (bf16)lo;
  z.h[1] = (bf16)hi;
  return z.u;
}

// ---------------- K0: per-batch masked count ----------------
__global__ void mask_count_kernel(const unsigned char* __restrict__ mask, int* __restrict__ nm) {
  int wid = threadIdx.x >> 6, lane = threadIdx.x & 63;
  if (wid >= BB) return;
  int s = 0;
  for (int i = lane; i < SS; i += 64) s += (mask[wid * SS + i] != 0) ? 1 : 0;
#pragma unroll
  for (int m = 1; m < 64; m <<= 1) s += __shfl_xor(s, m);
  if (lane == 0) nm[wid] = s;
}

// ---------------- K1: f32 -> bf16 convert ----------------
__global__ void cvt_kernel(const float* __restrict__ src, bf16* __restrict__ dst, int n4) {
  int stride = gridDim.x * blockDim.x;
  for (int i = blockIdx.x * blockDim.x + threadIdx.x; i < n4; i += stride) {
    float4 v = ((const float4*)src)[i];
    bf16x4 o;
    o[0] = (bf16)v.x; o[1] = (bf16)v.y; o[2] = (bf16)v.z; o[3] = (bf16)v.w;
    ((bf16x4*)dst)[i] = o;
  }
}

// ---------------- K2/K5: C[M,N] = A[M,K] @ B[N,K]^T ----------------
// 128x128 tile, XCD chunk-swizzled 1-D grid (nwg must be divisible by 8).
template <bool F32OUT>
__global__ void __launch_bounds__(256) gemm_bt_kernel(const bf16* __restrict__ A,
                                                      const bf16* __restrict__ Bm,
                                                      void* __restrict__ Cout,
                                                      int M, int N, int K) {
  __shared__ bf16 Ab[128 * 32];
  __shared__ bf16 Bb[128 * 32];
  const int tid = threadIdx.x;
  const int wid = tid >> 6, lane = tid & 63;
  const int lr = lane & 15, lg = lane >> 4;
  const int nx = N >> 7;
  const int cpx = gridDim.x >> 3;
  const int lid = (blockIdx.x & 7) * cpx + (blockIdx.x >> 3);
  const int m0 = (lid / nx) * 128, n0 = (lid % nx) * 128;
  const int wm = (wid >> 1) * 64, wn = (wid & 1) * 64;
  f32x4 acc[4][4] = {};
  for (int k0 = 0; k0 < K; k0 += 32) {
    __syncthreads();
#pragma unroll
    for (int i = 0; i < 2; ++i) {
      int o = (wid * 2 + i) * 1024 + lane * 16;
      int row = o >> 6;
      int ke = (o & 63) >> 1;
      gload_lds16(A + (size_t)(m0 + row) * K + k0 + ke, (char*)Ab + o);
      gload_lds16(Bm + (size_t)(n0 + row) * K + k0 + ke, (char*)Bb + o);
    }
    __syncthreads();
    bf16x8 af[4], bf_[4];
#pragma unroll
    for (int i = 0; i < 4; ++i) af[i] = *(const bf16x8*)&Ab[(wm + i * 16 + lr) * 32 + lg * 8];
#pragma unroll
    for (int j = 0; j < 4; ++j) bf_[j] = *(const bf16x8*)&Bb[(wn + j * 16 + lr) * 32 + lg * 8];
#pragma unroll
    for (int i = 0; i < 4; ++i)
#pragma unroll
      for (int j = 0; j < 4; ++j)
        acc[i][j] = __builtin_amdgcn_mfma_f32_16x16x32_bf16(af[i], bf_[j], acc[i][j], 0, 0, 0);
  }
#pragma unroll
  for (int i = 0; i < 4; ++i)
#pragma unroll
    for (int j = 0; j < 4; ++j)
#pragma unroll
      for (int r = 0; r < 4; ++r) {
        int row = m0 + wm + i * 16 + lg * 4 + r;
        int col = n0 + wn + j * 16 + lr;
        if (F32OUT)
          ((float*)Cout)[(size_t)row * N + col] = acc[i][j][r];
        else
          ((bf16*)Cout)[(size_t)row * N + col] = (bf16)acc[i][j][r];
      }
}

// ---------------- K3: RoPE + RMSNorm + per-dim scale + V transpose ----------------
// NOTE: folds LOG2E^2 (not LOG2E) into q scale so attention softmax can use exp2f.
__global__ void __launch_bounds__(256) rope_rms_kernel(
    const bf16* __restrict__ Qraw, const bf16* __restrict__ Kraw, const bf16* __restrict__ Vraw,
    const float* __restrict__ qls, const float* __restrict__ kls, const float* __restrict__ pds,
    const int* __restrict__ nm,
    bf16* __restrict__ Qp, bf16* __restrict__ Kp, bf16* __restrict__ Vt) {
  __shared__ bf16 Vlds[64][72];
  const int s0 = blockIdx.x * 64;
  const int bh = blockIdx.y;
  const int b = bh >> 4, h = bh & 15;
  const int wid = threadIdx.x >> 6, l = threadIdx.x & 63;
  const int nmb = nm[b];
  // (LOG2E^2 / sqrt(64)) * softplus(pds) * q_ln_scale ; LOG2E^2 = 2.0813689810056077
  const float qsc = qls[l] * 0.26017112262570096f * log1pf(__expf(pds[l]));
  const float ksc = kls[l];
  const float inv_ts = __expf((float)(l & 31) * (-9.210340371976184f / 32.0f));
  for (int i = 0; i < 16; ++i) {
    int s = s0 + wid * 16 + i;
    size_t off = ((size_t)(b * SS + s)) * DD + h * 64 + l;
    float q = (float)Qraw[off], k = (float)Kraw[off], v = (float)Vraw[off];
    float ang = (float)(s - nmb) * inv_ts;
    float sn, cs;
    sincosf(ang, &sn, &cs);
    float qo = __shfl_xor(q, 32), ko = __shfl_xor(k, 32);
    float qr = (l < 32) ? (q * cs - qo * sn) : (q * cs + qo * sn);
    float kr = (l < 32) ? (k * cs - ko * sn) : (k * cs + ko * sn);
    float sq = qr * qr, sk = kr * kr;
#pragma unroll
    for (int m = 1; m < 64; m <<= 1) {
      sq += __shfl_xor(sq, m);
      sk += __shfl_xor(sk, m);
    }
    float qout = qr * rsqrtf(sq * (1.0f / 64.0f) + 1e-6f) * qsc;
    float kout = kr * rsqrtf(sk * (1.0f / 64.0f) + 1e-6f) * ksc;
    size_t po = ((size_t)bh * SS + s) * 64 + l;
    Qp[po] = (bf16)qout;
    Kp[po] = (bf16)kout;
    Vlds[wid * 16 + i][l] = (bf16)v;
  }
  __syncthreads();
  int d = threadIdx.x >> 2, sc = (threadIdx.x & 3) * 16;
  bf16x8 v0, v1;
#pragma unroll
  for (int ii = 0; ii < 8; ++ii) v0[ii] = Vlds[sc + ii][d];
#pragma unroll
  for (int ii = 0; ii < 8; ++ii) v1[ii] = Vlds[sc + 8 + ii][d];
  size_t vo = ((size_t)bh * 64 + d) * SS + s0 + sc;
  *(bf16x8*)(Vt + vo) = v0;
  *(bf16x8*)(Vt + vo + 8) = v1;
}

// ---------------- K4: causal flash attention ----------------
// 128 q-rows/block (32/wave), KV tile 64 staged in double-buffered swizzled LDS.
// Swapped QK^T (A=K, B=Q) -> P lane-local per q-row; in-register softmax (exp2);
// shuffle-redistributed P as B-operand of swapped PV (A=Vt) -> q stays lane-local.
__global__ void __launch_bounds__(256) flash_kernel(
    const bf16* __restrict__ Qp, const bf16* __restrict__ Kp, const bf16* __restrict__ Vt,
    bf16* __restrict__ O, const int* __restrict__ nm) {
  __shared__ bf16 Kb[2][64 * 64];
  __shared__ bf16 Vb[2][64 * 64];
  // XCD chunk swizzle (bijective, nwg%8==0): each XCD owns 8 heads -> KV fits its L2.
  const int cpx = gridDim.x >> 3;
  const int lid = (blockIdx.x & 7) * cpx + (blockIdx.x >> 3);
  const int bh = lid >> 4;
  const int x = 15 - (lid & 15);  // reversed: biggest causal blocks dispatch first (LPT)
  const int b = bh >> 4, h = bh & 15;
  const int tid = threadIdx.x;
  const int wid = tid >> 6, lane = tid & 63;
  const int lr = lane & 15, lg = lane >> 4;
  const int nmb = nm[b];
  const int wq = x * 128 + wid * 32;

  // Q fragments (B-operand layout: col=q=lr, k=lg*8..+7)
  bf16x8 qf[2][2];
#pragma unroll
  for (int qi = 0; qi < 2; ++qi)
#pragma unroll
    for (int kh = 0; kh < 2; ++kh)
      qf[qi][kh] =
          *(const bf16x8*)(Qp + ((size_t)bh * SS + wq + qi * 16 + lr) * 64 + kh * 32 + lg * 8);

  float m_r[2] = {-1e30f, -1e30f};
  float l_r[2] = {0.f, 0.f};
  f32x4 o_acc[2][4] = {};

  const int nt = 2 * x + 2;

  auto STAGE = [&](int bi, int t) {
    const int kv0 = t * 64;
#pragma unroll
    for (int i = 0; i < 2; ++i) {
      int o = i * 4096 + tid * 16;
      int row = o >> 7;                       // 128B rows (64 bf16)
      int c16 = ((o >> 4) & 7) ^ (row & 7);   // pre-swizzled global source column group
      gload_lds16(Kp + ((size_t)bh * SS + kv0 + row) * 64 + c16 * 8, (char*)Kb[bi] + o);
      gload_lds16(Vt + ((size_t)bh * 64 + row) * SS + kv0 + c16 * 8, (char*)Vb[bi] + o);
    }
  };

  STAGE(0, 0);
  __syncthreads();
  int buf = 0;
  for (int t = 0; t < nt; ++t) {
    if (t + 1 < nt) STAGE(buf ^ 1, t + 1);  // prefetch overlaps compute; barrier drains vmcnt
    const int kv0 = t * 64;
    // ---- QK^T ----
    f32x4 s[2][4];
#pragma unroll
    for (int j = 0; j < 4; ++j) {
      int row = j * 16 + lr;
      const char* kbase = (const char*)Kb[buf] + row * 128;
      bf16x8 kf0 = *(const bf16x8*)(kbase + ((lg ^ (row & 7)) << 4));
      bf16x8 kf1 = *(const bf16x8*)(kbase + (((4 + lg) ^ (row & 7)) << 4));
      f32x4 z0 = {}, z1 = {};
      z0 = __builtin_amdgcn_mfma_f32_16x16x32_bf16(kf0, qf[0][0], z0, 0, 0, 0);
      z0 = __builtin_amdgcn_mfma_f32_16x16x32_bf16(kf1, qf[0][1], z0, 0, 0, 0);
      z1 = __builtin_amdgcn_mfma_f32_16x16x32_bf16(kf0, qf[1][0], z1, 0, 0, 0);
      z1 = __builtin_amdgcn_mfma_f32_16x16x32_bf16(kf1, qf[1][1], z1, 0, 0, 0);
      s[0][j] = z0;
      s[1][j] = z1;
    }
    // ---- masks (wave-uniform branches; most tiles skip) ----
    if (kv0 + 63 > wq) {
#pragma unroll
      for (int qi = 0; qi < 2; ++qi) {
        int qr = wq + qi * 16 + lr;
#pragma unroll
        for (int j = 0; j < 4; ++j) {
          int kvb = kv0 + j * 16 + lg * 4;
#pragma unroll
          for (int r = 0; r < 4; ++r)
            if (kvb + r > qr) s[qi][j][r] = -1e30f;
        }
      }
    }
    if (kv0 < nmb) {
#pragma unroll
      for (int j = 0; j < 4; ++j) {
        int kvb = kv0 + j * 16 + lg * 4;
#pragma unroll
        for (int r = 0; r < 4; ++r)
          if (kvb + r < nmb) { s[0][j][r] = -1e30f; s[1][j][r] = -1e30f; }
      }
    }
    // ---- online softmax (q-row = lr, lane-local) ----
    bf16x8 pb[2][2];
#pragma unroll
    for (int qi = 0; qi < 2; ++qi) {
      float pm = s[qi][0][0];
#pragma unroll
      for (int j = 0; j < 4; ++j)
#pragma unroll
        for (int r = 0; r < 4; ++r) pm = fmaxf(pm, s[qi][j][r]);
      pm = fmaxf(pm, __shfl_xor(pm, 16));
      pm = fmaxf(pm, __shfl_xor(pm, 32));
      float mn = fmaxf(m_r[qi], pm);
      float scl = exp2f(m_r[qi] - mn);
      m_r[qi] = mn;
      float rs = 0.f;
#pragma unroll
      for (int j = 0; j < 4; ++j)
#pragma unroll
        for (int r = 0; r < 4; ++r) {
          float p = exp2f(s[qi][j][r] - mn);
          s[qi][j][r] = p;
          rs += p;
        }
      rs += __shfl_xor(rs, 16);
      rs += __shfl_xor(rs, 32);
      l_r[qi] = l_r[qi] * scl + rs;
#pragma unroll
      for (int jd = 0; jd < 4; ++jd) o_acc[qi][jd] *= scl;
      // pack P (bf16 pairs) and redistribute into PV B-frag: lane needs P[q=lr][kv=kh*32+lg*8+e]
      u32 pk[4][2];
#pragma unroll
      for (int j = 0; j < 4; ++j)
#pragma unroll
        for (int hh = 0; hh < 2; ++hh)
          pk[j][hh] = pack2(s[qi][j][2 * hh], s[qi][j][2 * hh + 1]);
#pragma unroll
      for (int kh = 0; kh < 2; ++kh) {
        union { u32 u[4]; bf16x8 v; } w_;
#pragma unroll
        for (int w = 0; w < 4; ++w) {
          int srcLane = lr + 16 * ((lg & 1) * 2 + (w >> 1));
          u32 a = __shfl(pk[kh * 2 + 0][w & 1], srcLane);
          u32 c = __shfl(pk[kh * 2 + 1][w & 1], srcLane);
          w_.u[w] = (lg & 2) ? c : a;
        }
        pb[qi][kh] = w_.v;
      }
    }
    // ---- PV (A = Vt tile rows=d, B = P cols=q) ----
#pragma unroll
    for (int jd = 0; jd < 4; ++jd) {
      int row = jd * 16 + lr;
      const char* vbase = (const char*)Vb[buf] + row * 128;
      bf16x8 va0 = *(const bf16x8*)(vbase + ((lg ^ (row & 7)) << 4));
      bf16x8 va1 = *(const bf16x8*)(vbase + (((4 + lg) ^ (row & 7)) << 4));
      o_acc[0][jd] = __builtin_amdgcn_mfma_f32_16x16x32_bf16(va0, pb[0][0], o_acc[0][jd], 0, 0, 0);
      o_acc[0][jd] = __builtin_amdgcn_mfma_f32_16x16x32_bf16(va1, pb[0][1], o_acc[0][jd], 0, 0, 0);
      o_acc[1][jd] = __builtin_amdgcn_mfma_f32_16x16x32_bf16(va0, pb[1][0], o_acc[1][jd], 0, 0, 0);
      o_acc[1][jd] = __builtin_amdgcn_mfma_f32_16x16x32_bf16(va1, pb[1][1], o_acc[1][jd], 0, 0, 0);
    }
    __syncthreads();
    buf ^= 1;
  }
  // ---- epilogue: D col=q=lr, row=d=jd*16+lg*4+r -> 8B packed stores ----
#pragma unroll
  for (int qi = 0; qi < 2; ++qi) {
    float invl = 1.0f / l_r[qi];
    size_t rowoff = ((size_t)b * SS + wq + qi * 16 + lr) * DD + h * 64;
#pragma unroll
    for (int jd = 0; jd < 4; ++jd) {
      f32x4 ov = o_acc[qi][jd] * invl;
      bf16x4 hv;
      hv[0] = (bf16)ov[0]; hv[1] = (bf16)ov[1]; hv[2] = (bf16)ov[2]; hv[3] = (bf16)ov[3];
      *(bf16x4*)(O + rowoff + jd * 16 + lg * 4) = hv;
    }
  }
}

// ---------------- host launch ----------------
extern "C" void kernel_launch(void* const* d_in, const int* in_sizes, int n_in,
                              void* d_out, int out_size, void* d_ws, size_t ws_size,
                              hipStream_t stream) {
  const float* X = (const float*)d_in[0];
  const float* Wq = (const float*)d_in[1];
  const float* Wk = (const float*)d_in[2];
  const float* Wv = (const float*)d_in[3];
  const float* Wo = (const float*)d_in[4];
  const float* qls = (const float*)d_in[5];
  const float* kls = (const float*)d_in[6];
  const float* pds = (const float*)d_in[7];
  const unsigned char* mask = (const unsigned char*)d_in[8];

  char* ws = (char*)d_ws;
  size_t off = 0;
  auto alloc = [&](size_t bytes) {
    char* p = ws + off;
    off += (bytes + 255) & ~(size_t)255;
    return p;
  };
  const size_t NTOK = (size_t)BB * SS;  // 8192
  int* nm = (int*)alloc(16);
  bf16* Xb = (bf16*)alloc(NTOK * DD * 2);
  bf16* Wqb = (bf16*)alloc((size_t)DD * DD * 2);
  bf16* Wkb = (bf16*)alloc((size_t)DD * DD * 2);
  bf16* Wvb = (bf16*)alloc((size_t)DD * DD * 2);
  bf16* Wob = (bf16*)alloc((size_t)DD * DD * 2);
  bf16* Qraw = (bf16*)alloc(NTOK * DD * 2);
  bf16* Kraw = (bf16*)alloc(NTOK * DD * 2);
  bf16* Vraw = (bf16*)alloc(NTOK * DD * 2);
  bf16* Kp = (bf16*)alloc(NTOK * DD * 2);
  bf16* Vt = (bf16*)alloc(NTOK * DD * 2);
  bf16* Qp = Xb;     // alias: Xb dead after QKV GEMMs
  bf16* Oat = Qraw;  // alias: Qraw dead after rope kernel

  mask_count_kernel<<<1, 256, 0, stream>>>(mask, nm);
  cvt_kernel<<<1024, 256, 0, stream>>>(X, Xb, (int)(NTOK * DD / 4));
  cvt_kernel<<<256, 256, 0, stream>>>(Wq, Wqb, DD * DD / 4);
  cvt_kernel<<<256, 256, 0, stream>>>(Wk, Wkb, DD * DD / 4);
  cvt_kernel<<<256, 256, 0, stream>>>(Wv, Wvb, DD * DD / 4);
  cvt_kernel<<<256, 256, 0, stream>>>(Wo, Wob, DD * DD / 4);

  const int gemm_blocks = (int)(NTOK / 128) * (DD / 128);  // 512, %8==0
  gemm_bt_kernel<false><<<gemm_blocks, 256, 0, stream>>>(Xb, Wqb, Qraw, (int)NTOK, DD, DD);
  gemm_bt_kernel<false><<<gemm_blocks, 256, 0, stream>>>(Xb, Wkb, Kraw, (int)NTOK, DD, DD);
  gemm_bt_kernel<false><<<gemm_blocks, 256, 0, stream>>>(Xb, Wvb, Vraw, (int)NTOK, DD, DD);

  rope_rms_kernel<<<dim3(SS / 64, BB * HH), 256, 0, stream>>>(Qraw, Kraw, Vraw, qls, kls, pds,
                                                              nm, Qp, Kp, Vt);
  flash_kernel<<<SS / 128 * BB * HH, 256, 0, stream>>>(Qp, Kp, Vt, Oat, nm);
  gemm_bt_kernel<true><<<gemm_blocks, 256, 0, stream>>>(Oat, Wob, d_out, (int)NTOK, DD, DD);
}

// Round 3
// 276.526 us; speedup vs baseline: 2.2663x; 1.2225x over previous
//
#include <hip/hip_runtime.h>
#include <cstdint>
#include <cstddef>

#define BB 4
#define SS 2048
#define DD 1024
#define HH 16

typedef __bf16 bf16;
typedef __bf16 bf16x8 __attribute__((ext_vector_type(8)));
typedef __bf16 bf16x4 __attribute__((ext_vector_type(4)));
typedef float f32x4 __attribute__((ext_vector_type(4)));
typedef unsigned int u32;

typedef __attribute__((address_space(1))) const void* as1_cvoid;
typedef __attribute__((address_space(3))) void* as3_void;

__device__ __forceinline__ void gload_lds16(const void* g, void* l) {
  __builtin_amdgcn_global_load_lds((as1_cvoid)g, (as3_void)l, 16, 0, 0);
}

__device__ __forceinline__ u32 pack2(float lo, float hi) {
  union { bf16 h[2]; u32 u; } z;
  z.h[0] = (bf16)lo;
  z.h[1] = (bf16)hi;
  return z.u;
}

// ---------------- K0: per-batch masked count ----------------
__global__ void mask_count_kernel(const unsigned char* __restrict__ mask, int* __restrict__ nm) {
  int wid = threadIdx.x >> 6, lane = threadIdx.x & 63;
  if (wid >= BB) return;
  int s = 0;
  for (int i = lane; i < SS; i += 64) s += (mask[wid * SS + i] != 0) ? 1 : 0;
#pragma unroll
  for (int m = 1; m < 64; m <<= 1) s += __shfl_xor(s, m);
  if (lane == 0) nm[wid] = s;
}

// ---------------- K1: f32 -> bf16 convert ----------------
__global__ void cvt_kernel(const float* __restrict__ src, bf16* __restrict__ dst, int n4) {
  int stride = gridDim.x * blockDim.x;
  for (int i = blockIdx.x * blockDim.x + threadIdx.x; i < n4; i += stride) {
    float4 v = ((const float4*)src)[i];
    bf16x4 o;
    o[0] = (bf16)v.x; o[1] = (bf16)v.y; o[2] = (bf16)v.z; o[3] = (bf16)v.w;
    ((bf16x4*)dst)[i] = o;
  }
}

// ---------------- K2/K5: C[M,N] = A[M,K] @ B[N,K]^T ----------------
template <bool F32OUT>
__global__ void __launch_bounds__(256) gemm_bt_kernel(const bf16* __restrict__ A,
                                                      const bf16* __restrict__ Bm,
                                                      void* __restrict__ Cout,
                                                      int M, int N, int K) {
  __shared__ bf16 Ab[128 * 32];
  __shared__ bf16 Bb[128 * 32];
  const int tid = threadIdx.x;
  const int wid = tid >> 6, lane = tid & 63;
  const int lr = lane & 15, lg = lane >> 4;
  const int nx = N >> 7;
  const int cpx = gridDim.x >> 3;
  const int lid = (blockIdx.x & 7) * cpx + (blockIdx.x >> 3);
  const int m0 = (lid / nx) * 128, n0 = (lid % nx) * 128;
  const int wm = (wid >> 1) * 64, wn = (wid & 1) * 64;
  f32x4 acc[4][4] = {};
  for (int k0 = 0; k0 < K; k0 += 32) {
    __syncthreads();
#pragma unroll
    for (int i = 0; i < 2; ++i) {
      int o = (wid * 2 + i) * 1024 + lane * 16;
      int row = o >> 6;
      int ke = (o & 63) >> 1;
      gload_lds16(A + (size_t)(m0 + row) * K + k0 + ke, (char*)Ab + o);
      gload_lds16(Bm + (size_t)(n0 + row) * K + k0 + ke, (char*)Bb + o);
    }
    __syncthreads();
    bf16x8 af[4], bf_[4];
#pragma unroll
    for (int i = 0; i < 4; ++i) af[i] = *(const bf16x8*)&Ab[(wm + i * 16 + lr) * 32 + lg * 8];
#pragma unroll
    for (int j = 0; j < 4; ++j) bf_[j] = *(const bf16x8*)&Bb[(wn + j * 16 + lr) * 32 + lg * 8];
#pragma unroll
    for (int i = 0; i < 4; ++i)
#pragma unroll
      for (int j = 0; j < 4; ++j)
        acc[i][j] = __builtin_amdgcn_mfma_f32_16x16x32_bf16(af[i], bf_[j], acc[i][j], 0, 0, 0);
  }
#pragma unroll
  for (int i = 0; i < 4; ++i)
#pragma unroll
    for (int j = 0; j < 4; ++j)
#pragma unroll
      for (int r = 0; r < 4; ++r) {
        int row = m0 + wm + i * 16 + lg * 4 + r;
        int col = n0 + wn + j * 16 + lr;
        if (F32OUT)
          ((float*)Cout)[(size_t)row * N + col] = acc[i][j][r];
        else
          ((bf16*)Cout)[(size_t)row * N + col] = (bf16)acc[i][j][r];
      }
}

// ---------------- K3: RoPE + RMSNorm + per-dim scale + V transpose ----------------
// Folds LOG2E^2 into q scale so attention softmax can use exp2f.
__global__ void __launch_bounds__(256) rope_rms_kernel(
    const bf16* __restrict__ Qraw, const bf16* __restrict__ Kraw, const bf16* __restrict__ Vraw,
    const float* __restrict__ qls, const float* __restrict__ kls, const float* __restrict__ pds,
    const int* __restrict__ nm,
    bf16* __restrict__ Qp, bf16* __restrict__ Kp, bf16* __restrict__ Vt) {
  __shared__ bf16 Vlds[64][72];
  const int s0 = blockIdx.x * 64;
  const int bh = blockIdx.y;
  const int b = bh >> 4, h = bh & 15;
  const int wid = threadIdx.x >> 6, l = threadIdx.x & 63;
  const int nmb = nm[b];
  const float qsc = qls[l] * 0.26017112262570096f * log1pf(__expf(pds[l]));
  const float ksc = kls[l];
  const float inv_ts = __expf((float)(l & 31) * (-9.210340371976184f / 32.0f));
  for (int i = 0; i < 16; ++i) {
    int s = s0 + wid * 16 + i;
    size_t off = ((size_t)(b * SS + s)) * DD + h * 64 + l;
    float q = (float)Qraw[off], k = (float)Kraw[off], v = (float)Vraw[off];
    float ang = (float)(s - nmb) * inv_ts;
    float sn, cs;
    sincosf(ang, &sn, &cs);
    float qo = __shfl_xor(q, 32), ko = __shfl_xor(k, 32);
    float qr = (l < 32) ? (q * cs - qo * sn) : (q * cs + qo * sn);
    float kr = (l < 32) ? (k * cs - ko * sn) : (k * cs + ko * sn);
    float sq = qr * qr, sk = kr * kr;
#pragma unroll
    for (int m = 1; m < 64; m <<= 1) {
      sq += __shfl_xor(sq, m);
      sk += __shfl_xor(sk, m);
    }
    float qout = qr * rsqrtf(sq * (1.0f / 64.0f) + 1e-6f) * qsc;
    float kout = kr * rsqrtf(sk * (1.0f / 64.0f) + 1e-6f) * ksc;
    size_t po = ((size_t)bh * SS + s) * 64 + l;
    Qp[po] = (bf16)qout;
    Kp[po] = (bf16)kout;
    Vlds[wid * 16 + i][l] = (bf16)v;
  }
  __syncthreads();
  int d = threadIdx.x >> 2, sc = (threadIdx.x & 3) * 16;
  bf16x8 v0, v1;
#pragma unroll
  for (int ii = 0; ii < 8; ++ii) v0[ii] = Vlds[sc + ii][d];
#pragma unroll
  for (int ii = 0; ii < 8; ++ii) v1[ii] = Vlds[sc + 8 + ii][d];
  size_t vo = ((size_t)bh * 64 + d) * SS + s0 + sc;
  *(bf16x8*)(Vt + vo) = v0;
  *(bf16x8*)(Vt + vo + 8) = v1;
}

// ---------------- K4: causal flash attention, paired-strip balanced ----------------
// Each block: q-strips xA=15-px and xB=px (128 rows each) -> exactly 34 compute-tiles
// per block. KV tile 64 double-buffered in swizzled LDS (shared by both strips).
// Swapped QK^T; defer-max online softmax (no cross-lane in steady state); P through
// per-wave LDS u32 round-trip into PV B-fragments.
__global__ void __launch_bounds__(256, 3) flash_kernel(
    const bf16* __restrict__ Qp, const bf16* __restrict__ Kp, const bf16* __restrict__ Vt,
    bf16* __restrict__ O, const int* __restrict__ nm) {
  __shared__ bf16 Kb[2][64 * 64];
  __shared__ bf16 Vb[2][64 * 64];
  __shared__ u32 Pl[4][2][16][36];
  const int cpx = gridDim.x >> 3;  // 64
  const int lid = (blockIdx.x & 7) * cpx + (blockIdx.x >> 3);
  const int bh = lid >> 3;
  const int px = lid & 7;
  const int b = bh >> 4, h = bh & 15;
  const int tid = threadIdx.x;
  const int wid = tid >> 6, lane = tid & 63;
  const int lr = lane & 15, lg = lane >> 4;
  const int nmb = nm[b];
  const int xs[2] = {15 - px, px};            // strip A (deep), strip B (shallow)
  const int wqs[2] = {xs[0] * 128 + wid * 32, xs[1] * 128 + wid * 32};
  const int ntA = 2 * xs[0] + 2;

  // Q fragments, both strips (B-operand: col=q=lr, k=lg*8..+7)
  bf16x8 qf[2][2][2];
#pragma unroll
  for (int st = 0; st < 2; ++st)
#pragma unroll
    for (int qi = 0; qi < 2; ++qi)
#pragma unroll
      for (int kh = 0; kh < 2; ++kh)
        qf[st][qi][kh] = *(const bf16x8*)(Qp + ((size_t)bh * SS + wqs[st] + qi * 16 + lr) * 64 +
                                          kh * 32 + lg * 8);

  float m_r[2][2] = {{-1e30f, -1e30f}, {-1e30f, -1e30f}};
  float l_p[2][2] = {{0.f, 0.f}, {0.f, 0.f}};
  f32x4 o_acc[2][2][4] = {};

  auto STAGE = [&](int bi, int t) {
    const int kv0 = t * 64;
#pragma unroll
    for (int i = 0; i < 2; ++i) {
      int o = i * 4096 + tid * 16;
      int row = o >> 7;
      int c16 = ((o >> 4) & 7) ^ (row & 7);
      gload_lds16(Kp + ((size_t)bh * SS + kv0 + row) * 64 + c16 * 8, (char*)Kb[bi] + o);
      gload_lds16(Vt + ((size_t)bh * 64 + row) * SS + kv0 + c16 * 8, (char*)Vb[bi] + o);
    }
  };

  STAGE(0, 0);
  __syncthreads();
  int buf = 0;
  for (int t = 0; t < ntA; ++t) {
    if (t + 1 < ntA) STAGE(buf ^ 1, t + 1);
    const int kv0 = t * 64;
#pragma unroll
    for (int st = 0; st < 2; ++st) {
      const int wq = wqs[st];
      if (kv0 > wq + 31) continue;  // fully masked for this wave's strip (wave-uniform)
      // ---- per-qi: QK^T -> softmax -> P to LDS ----
#pragma unroll
      for (int qi = 0; qi < 2; ++qi) {
        f32x4 s[4];
#pragma unroll
        for (int j = 0; j < 4; ++j) {
          int row = j * 16 + lr;
          const char* kbase = (const char*)Kb[buf] + row * 128;
          bf16x8 kf0 = *(const bf16x8*)(kbase + ((lg ^ (row & 7)) << 4));
          bf16x8 kf1 = *(const bf16x8*)(kbase + (((4 + lg) ^ (row & 7)) << 4));
          f32x4 z = {};
          z = __builtin_amdgcn_mfma_f32_16x16x32_bf16(kf0, qf[st][qi][0], z, 0, 0, 0);
          z = __builtin_amdgcn_mfma_f32_16x16x32_bf16(kf1, qf[st][qi][1], z, 0, 0, 0);
          s[j] = z;
        }
        if (kv0 + 63 > wq) {  // causal mask
          int qr = wq + qi * 16 + lr;
#pragma unroll
          for (int j = 0; j < 4; ++j) {
            int kvb = kv0 + j * 16 + lg * 4;
#pragma unroll
            for (int r = 0; r < 4; ++r)
              if (kvb + r > qr) s[j][r] = -1e30f;
          }
        }
        if (kv0 < nmb) {  // prefix-padding mask
#pragma unroll
          for (int j = 0; j < 4; ++j) {
            int kvb = kv0 + j * 16 + lg * 4;
#pragma unroll
            for (int r = 0; r < 4; ++r)
              if (kvb + r < nmb) s[j][r] = -1e30f;
          }
        }
        // per-lane partial max (16 kv values)
        float pm = s[0][0];
#pragma unroll
        for (int j = 0; j < 4; ++j)
#pragma unroll
          for (int r = 0; r < 4; ++r) pm = fmaxf(pm, s[j][r]);
        // defer-max: only rescale when max grows past threshold (exp2 domain, THR=8)
        if (!__all(pm - m_r[st][qi] <= 8.f)) {
          pm = fmaxf(pm, __shfl_xor(pm, 16));
          pm = fmaxf(pm, __shfl_xor(pm, 32));
          float mn = fmaxf(m_r[st][qi], pm);
          float scl = exp2f(m_r[st][qi] - mn);
          m_r[st][qi] = mn;
          l_p[st][qi] *= scl;
          f32x4 sv = {scl, scl, scl, scl};
#pragma unroll
          for (int jd = 0; jd < 4; ++jd) o_acc[st][qi][jd] *= sv;
        }
        const float mloc = m_r[st][qi];
        float lp = l_p[st][qi];
        u32 pk[4][2];
#pragma unroll
        for (int j = 0; j < 4; ++j) {
          float p0 = exp2f(s[j][0] - mloc), p1 = exp2f(s[j][1] - mloc);
          float p2 = exp2f(s[j][2] - mloc), p3 = exp2f(s[j][3] - mloc);
          lp += (p0 + p1) + (p2 + p3);
          pk[j][0] = pack2(p0, p1);
          pk[j][1] = pack2(p2, p3);
        }
        l_p[st][qi] = lp;
#pragma unroll
        for (int j = 0; j < 4; ++j) {
          uint2 w2;
          w2.x = pk[j][0];
          w2.y = pk[j][1];
          *(uint2*)&Pl[wid][qi][lr][j * 8 + lg * 2] = w2;  // slots j*8+lg*2, +1 (kv pairs)
        }
      }
      // ---- gather PV B-fragments (k=kv=lg*8.., col=q=lr) ----
      bf16x8 pb[2][2];
#pragma unroll
      for (int qi = 0; qi < 2; ++qi)
#pragma unroll
        for (int kh = 0; kh < 2; ++kh)
          pb[qi][kh] = *(const bf16x8*)&Pl[wid][qi][lr][kh * 16 + lg * 4];
      // ---- PV ----
#pragma unroll
      for (int jd = 0; jd < 4; ++jd) {
        int row = jd * 16 + lr;
        const char* vbase = (const char*)Vb[buf] + row * 128;
        bf16x8 va0 = *(const bf16x8*)(vbase + ((lg ^ (row & 7)) << 4));
        bf16x8 va1 = *(const bf16x8*)(vbase + (((4 + lg) ^ (row & 7)) << 4));
        o_acc[st][0][jd] =
            __builtin_amdgcn_mfma_f32_16x16x32_bf16(va0, pb[0][0], o_acc[st][0][jd], 0, 0, 0);
        o_acc[st][0][jd] =
            __builtin_amdgcn_mfma_f32_16x16x32_bf16(va1, pb[0][1], o_acc[st][0][jd], 0, 0, 0);
        o_acc[st][1][jd] =
            __builtin_amdgcn_mfma_f32_16x16x32_bf16(va0, pb[1][0], o_acc[st][1][jd], 0, 0, 0);
        o_acc[st][1][jd] =
            __builtin_amdgcn_mfma_f32_16x16x32_bf16(va1, pb[1][1], o_acc[st][1][jd], 0, 0, 0);
      }
    }
    __syncthreads();
    buf ^= 1;
  }
  // ---- epilogue: reduce deferred l across lane-groups, normalize, store ----
#pragma unroll
  for (int st = 0; st < 2; ++st)
#pragma unroll
    for (int qi = 0; qi < 2; ++qi) {
      float l = l_p[st][qi];
      l += __shfl_xor(l, 16);
      l += __shfl_xor(l, 32);
      float invl = 1.0f / l;
      size_t rowoff = ((size_t)b * SS + wqs[st] + qi * 16 + lr) * DD + h * 64;
#pragma unroll
      for (int jd = 0; jd < 4; ++jd) {
        f32x4 ov = o_acc[st][qi][jd] * invl;
        bf16x4 hv;
        hv[0] = (bf16)ov[0]; hv[1] = (bf16)ov[1]; hv[2] = (bf16)ov[2]; hv[3] = (bf16)ov[3];
        *(bf16x4*)(O + rowoff + jd * 16 + lg * 4) = hv;
      }
    }
}

// ---------------- host launch ----------------
extern "C" void kernel_launch(void* const* d_in, const int* in_sizes, int n_in,
                              void* d_out, int out_size, void* d_ws, size_t ws_size,
                              hipStream_t stream) {
  const float* X = (const float*)d_in[0];
  const float* Wq = (const float*)d_in[1];
  const float* Wk = (const float*)d_in[2];
  const float* Wv = (const float*)d_in[3];
  const float* Wo = (const float*)d_in[4];
  const float* qls = (const float*)d_in[5];
  const float* kls = (const float*)d_in[6];
  const float* pds = (const float*)d_in[7];
  const unsigned char* mask = (const unsigned char*)d_in[8];

  char* ws = (char*)d_ws;
  size_t off = 0;
  auto alloc = [&](size_t bytes) {
    char* p = ws + off;
    off += (bytes + 255) & ~(size_t)255;
    return p;
  };
  const size_t NTOK = (size_t)BB * SS;  // 8192
  int* nm = (int*)alloc(16);
  bf16* Xb = (bf16*)alloc(NTOK * DD * 2);
  bf16* Wqb = (bf16*)alloc((size_t)DD * DD * 2);
  bf16* Wkb = (bf16*)alloc((size_t)DD * DD * 2);
  bf16* Wvb = (bf16*)alloc((size_t)DD * DD * 2);
  bf16* Wob = (bf16*)alloc((size_t)DD * DD * 2);
  bf16* Qraw = (bf16*)alloc(NTOK * DD * 2);
  bf16* Kraw = (bf16*)alloc(NTOK * DD * 2);
  bf16* Vraw = (bf16*)alloc(NTOK * DD * 2);
  bf16* Kp = (bf16*)alloc(NTOK * DD * 2);
  bf16* Vt = (bf16*)alloc(NTOK * DD * 2);
  bf16* Qp = Xb;     // alias: Xb dead after QKV GEMMs
  bf16* Oat = Qraw;  // alias: Qraw dead after rope kernel

  mask_count_kernel<<<1, 256, 0, stream>>>(mask, nm);
  cvt_kernel<<<1024, 256, 0, stream>>>(X, Xb, (int)(NTOK * DD / 4));
  cvt_kernel<<<256, 256, 0, stream>>>(Wq, Wqb, DD * DD / 4);
  cvt_kernel<<<256, 256, 0, stream>>>(Wk, Wkb, DD * DD / 4);
  cvt_kernel<<<256, 256, 0, stream>>>(Wv, Wvb, DD * DD / 4);
  cvt_kernel<<<256, 256, 0, stream>>>(Wo, Wob, DD * DD / 4);

  const int gemm_blocks = (int)(NTOK / 128) * (DD / 128);  // 512, %8==0
  gemm_bt_kernel<false><<<gemm_blocks, 256, 0, stream>>>(Xb, Wqb, Qraw, (int)NTOK, DD, DD);
  gemm_bt_kernel<false><<<gemm_blocks, 256, 0, stream>>>(Xb, Wkb, Kraw, (int)NTOK, DD, DD);
  gemm_bt_kernel<false><<<gemm_blocks, 256, 0, stream>>>(Xb, Wvb, Vraw, (int)NTOK, DD, DD);

  rope_rms_kernel<<<dim3(SS / 64, BB * HH), 256, 0, stream>>>(Qraw, Kraw, Vraw, qls, kls, pds,
                                                              nm, Qp, Kp, Vt);
  flash_kernel<<<512, 256, 0, stream>>>(Qp, Kp, Vt, Oat, nm);
  gemm_bt_kernel<true><<<gemm_blocks, 256, 0, stream>>>(Oat, Wob, d_out, (int)NTOK, DD, DD);
}